// Round 1
// baseline (2056.364 us; speedup 1.0000x reference)
//
#include <hip/hip_runtime.h>
#include <hip/hip_bf16.h>
#include <cstdint>
#include <cstddef>

#define D_MODEL 1024
#define N_EXP   8
#define HID     4096
#define T_TOK   4096          // B*S
#define NPAIR   (T_TOK * 2)   // top-2

// ---------------- workspace layout (bytes) ----------------
// 0       counts[8]      int
// 32      cursor[8]      int
// 64      offsets[8]     int
// 128     tok_e[T][2]    int    (32768 B)
// 32896   tok_g[T][2]    float  (32768 B)
// 65664   list_tok[NPAIR] int   (32768 B)
// 98432   list_gate[NPAIR] float(32768 B)
// 131328  H[NPAIR][HID]  float  (134217728 B)
#define WS_COUNTS   0
#define WS_CURSOR   32
#define WS_OFFSETS  64
#define WS_TOKE     128
#define WS_TOKG     32896
#define WS_LTOK     65664
#define WS_LGATE    98432
#define WS_H        131328

// ---------------------------------------------------------------------------
// Router: logits = x@Wr + br + softplus(x@Wn + bn) * noise ; top-2 ; softmax.
// One 256-thread block per token. tid = g*8 + e, g in [0,32), e in [0,8).
// ---------------------------------------------------------------------------
__global__ __launch_bounds__(256) void k_router(
    const float* __restrict__ x, const float* __restrict__ noise,
    const float* __restrict__ Wr, const float* __restrict__ br,
    const float* __restrict__ Wn, const float* __restrict__ bn,
    int* __restrict__ counts, int* __restrict__ tok_e, float* __restrict__ tok_g)
{
    const int t   = blockIdx.x;
    const int tid = threadIdx.x;
    const int e   = tid & 7;
    const int g   = tid >> 3;
    const float* xr = x + (size_t)t * D_MODEL;

    float ar = 0.f, an = 0.f;
    const int ibase = g * 32;
    #pragma unroll 8
    for (int j = 0; j < 32; ++j) {
        const int i = ibase + j;
        const float xv = xr[i];
        ar = fmaf(xv, Wr[i * 8 + e], ar);
        an = fmaf(xv, Wn[i * 8 + e], an);
    }

    __shared__ float sR[256], sN[256];
    sR[tid] = ar; sN[tid] = an;
    __syncthreads();
    for (int off = 128; off >= 8; off >>= 1) {
        if (tid < off) { sR[tid] += sR[tid + off]; sN[tid] += sN[tid + off]; }
        __syncthreads();
    }

    __shared__ float lg[8];
    if (tid < 8) {
        const float z  = sN[tid] + bn[tid];
        // softplus(z) = max(z,0) + log1p(exp(-|z|))  (matches jax.nn.softplus)
        const float sp = fmaxf(z, 0.f) + log1pf(expf(-fabsf(z)));
        lg[tid] = sR[tid] + br[tid] + sp * noise[t * 8 + tid];
    }
    __syncthreads();

    if (tid == 0) {
        float v0 = -INFINITY, v1 = -INFINITY;
        int   i0 = 0,         i1 = 0;
        #pragma unroll
        for (int ee = 0; ee < 8; ++ee) {
            const float v = lg[ee];
            if (v > v0)      { v1 = v0; i1 = i0; v0 = v; i0 = ee; }
            else if (v > v1) { v1 = v;  i1 = ee; }
        }
        // softmax over [v0, v1] with v0 >= v1
        const float ew  = expf(v1 - v0);
        const float inv = 1.f / (1.f + ew);
        tok_e[t * 2 + 0] = i0;
        tok_e[t * 2 + 1] = i1;
        tok_g[t * 2 + 0] = inv;
        tok_g[t * 2 + 1] = ew * inv;
        atomicAdd(&counts[i0], 1);
        atomicAdd(&counts[i1], 1);
    }
}

__global__ void k_prefix(const int* __restrict__ counts, int* __restrict__ offsets)
{
    if (threadIdx.x == 0 && blockIdx.x == 0) {
        int acc = 0;
        #pragma unroll
        for (int e = 0; e < N_EXP; ++e) { offsets[e] = acc; acc += counts[e]; }
    }
}

__global__ __launch_bounds__(256) void k_scatter(
    const int* __restrict__ tok_e, const float* __restrict__ tok_g,
    const int* __restrict__ offsets, int* __restrict__ cursor,
    int* __restrict__ list_tok, float* __restrict__ list_gate)
{
    const int gid = blockIdx.x * 256 + threadIdx.x;
    if (gid >= NPAIR) return;
    const int e = tok_e[gid];
    const int p = atomicAdd(&cursor[e], 1);
    const int slot = offsets[e] + p;
    list_tok[slot]  = gid >> 1;   // token id
    list_gate[slot] = tok_g[gid];
}

// ---------------------------------------------------------------------------
// Grouped GEMM1: H[slot, :] = relu( x[tok[slot], :] @ W1[e] + b1[e] )
// Tile: BM=64 tokens x BN=64 hidden, BK=32. 256 threads, 4x4 micro-tile.
// grid = (HID/64, 32, N_EXP); m-tiles strided by gridDim.y with early exit.
// ---------------------------------------------------------------------------
__global__ __launch_bounds__(256) void k_ffn1(
    const float* __restrict__ x, const float* __restrict__ W1,
    const float* __restrict__ b1,
    const int* __restrict__ counts, const int* __restrict__ offsets,
    const int* __restrict__ list_tok, float* __restrict__ H)
{
    const int e    = blockIdx.z;
    const int cnt  = counts[e];
    const int base = offsets[e];
    const int n0   = blockIdx.x * 64;
    const float* __restrict__ W1e = W1 + (size_t)e * D_MODEL * HID;

    __shared__ float As[64][36];   // [m][k], padded: float4-aligned, conflict-free
    __shared__ float Bs[32][68];   // [k][n], padded
    __shared__ int   stok[64];

    const int tid = threadIdx.x;
    const int tx  = tid & 15;      // n-group
    const int ty  = tid >> 4;      // m-group

    for (int mt = blockIdx.y; mt * 64 < cnt; mt += gridDim.y) {
        const int m0   = mt * 64;
        const int rows = min(64, cnt - m0);

        if (tid < 64) {
            const int r = m0 + tid;
            stok[tid] = list_tok[base + min(r, cnt - 1)];
        }

        float acc[4][4] = {};

        for (int kt = 0; kt < D_MODEL; kt += 32) {
            __syncthreads();   // prev compute done / stok ready
            #pragma unroll
            for (int p = 0; p < 2; ++p) {
                const int idx = p * 256 + tid;
                const int ar  = idx >> 3;            // 0..63
                const int aq  = (idx & 7) << 2;      // 0..28
                const float4 av = *(const float4*)(x + (size_t)stok[ar] * D_MODEL + kt + aq);
                *(float4*)&As[ar][aq] = av;
                const int brw = idx >> 4;            // 0..31
                const int bq  = (idx & 15) << 2;     // 0..60
                const float4 bv = *(const float4*)(W1e + (size_t)(kt + brw) * HID + n0 + bq);
                *(float4*)&Bs[brw][bq] = bv;
            }
            __syncthreads();
            #pragma unroll
            for (int kk = 0; kk < 32; ++kk) {
                const float a0 = As[ty * 4 + 0][kk];
                const float a1 = As[ty * 4 + 1][kk];
                const float a2 = As[ty * 4 + 2][kk];
                const float a3 = As[ty * 4 + 3][kk];
                const float4 b = *(const float4*)&Bs[kk][tx * 4];
                acc[0][0] = fmaf(a0, b.x, acc[0][0]); acc[0][1] = fmaf(a0, b.y, acc[0][1]);
                acc[0][2] = fmaf(a0, b.z, acc[0][2]); acc[0][3] = fmaf(a0, b.w, acc[0][3]);
                acc[1][0] = fmaf(a1, b.x, acc[1][0]); acc[1][1] = fmaf(a1, b.y, acc[1][1]);
                acc[1][2] = fmaf(a1, b.z, acc[1][2]); acc[1][3] = fmaf(a1, b.w, acc[1][3]);
                acc[2][0] = fmaf(a2, b.x, acc[2][0]); acc[2][1] = fmaf(a2, b.y, acc[2][1]);
                acc[2][2] = fmaf(a2, b.z, acc[2][2]); acc[2][3] = fmaf(a2, b.w, acc[2][3]);
                acc[3][0] = fmaf(a3, b.x, acc[3][0]); acc[3][1] = fmaf(a3, b.y, acc[3][1]);
                acc[3][2] = fmaf(a3, b.z, acc[3][2]); acc[3][3] = fmaf(a3, b.w, acc[3][3]);
            }
        }

        const float4 b1v = *(const float4*)(b1 + (size_t)e * HID + n0 + tx * 4);
        #pragma unroll
        for (int i = 0; i < 4; ++i) {
            const int m = ty * 4 + i;
            if (m < rows) {
                float4 hv;
                hv.x = fmaxf(acc[i][0] + b1v.x, 0.f);
                hv.y = fmaxf(acc[i][1] + b1v.y, 0.f);
                hv.z = fmaxf(acc[i][2] + b1v.z, 0.f);
                hv.w = fmaxf(acc[i][3] + b1v.w, 0.f);
                *(float4*)(H + (size_t)(base + m0 + m) * HID + n0 + tx * 4) = hv;
            }
        }
        __syncthreads();   // protect stok before next m-tile rewrites it
    }
}

// ---------------------------------------------------------------------------
// Grouped GEMM2: out[tok, :] += gate * ( H[slot, :] @ W2[e] + b2[e] )
// Same tiling, K = HID = 4096. f32 HW atomics (each out elem gets 2 adds).
// ---------------------------------------------------------------------------
__global__ __launch_bounds__(256) void k_ffn2(
    const float* __restrict__ H, const float* __restrict__ W2,
    const float* __restrict__ b2,
    const int* __restrict__ counts, const int* __restrict__ offsets,
    const int* __restrict__ list_tok, const float* __restrict__ list_gate,
    float* __restrict__ out)
{
    const int e    = blockIdx.z;
    const int cnt  = counts[e];
    const int base = offsets[e];
    const int n0   = blockIdx.x * 64;
    const float* __restrict__ W2e = W2 + (size_t)e * HID * D_MODEL;

    __shared__ float As[64][36];
    __shared__ float Bs[32][68];
    __shared__ int   stok[64];
    __shared__ float sg[64];

    const int tid = threadIdx.x;
    const int tx  = tid & 15;
    const int ty  = tid >> 4;

    for (int mt = blockIdx.y; mt * 64 < cnt; mt += gridDim.y) {
        const int m0   = mt * 64;
        const int rows = min(64, cnt - m0);

        if (tid < 64) {
            const int r  = m0 + tid;
            const int cr = min(r, cnt - 1);
            stok[tid] = list_tok[base + cr];
            sg[tid]   = list_gate[base + cr];
        }

        float acc[4][4] = {};

        for (int kt = 0; kt < HID; kt += 32) {
            __syncthreads();
            #pragma unroll
            for (int p = 0; p < 2; ++p) {
                const int idx = p * 256 + tid;
                const int ar  = idx >> 3;
                const int aq  = (idx & 7) << 2;
                const int slot = base + m0 + min(ar, rows - 1);
                const float4 av = *(const float4*)(H + (size_t)slot * HID + kt + aq);
                *(float4*)&As[ar][aq] = av;
                const int brw = idx >> 4;
                const int bq  = (idx & 15) << 2;
                const float4 bv = *(const float4*)(W2e + (size_t)(kt + brw) * D_MODEL + n0 + bq);
                *(float4*)&Bs[brw][bq] = bv;
            }
            __syncthreads();
            #pragma unroll
            for (int kk = 0; kk < 32; ++kk) {
                const float a0 = As[ty * 4 + 0][kk];
                const float a1 = As[ty * 4 + 1][kk];
                const float a2 = As[ty * 4 + 2][kk];
                const float a3 = As[ty * 4 + 3][kk];
                const float4 b = *(const float4*)&Bs[kk][tx * 4];
                acc[0][0] = fmaf(a0, b.x, acc[0][0]); acc[0][1] = fmaf(a0, b.y, acc[0][1]);
                acc[0][2] = fmaf(a0, b.z, acc[0][2]); acc[0][3] = fmaf(a0, b.w, acc[0][3]);
                acc[1][0] = fmaf(a1, b.x, acc[1][0]); acc[1][1] = fmaf(a1, b.y, acc[1][1]);
                acc[1][2] = fmaf(a1, b.z, acc[1][2]); acc[1][3] = fmaf(a1, b.w, acc[1][3]);
                acc[2][0] = fmaf(a2, b.x, acc[2][0]); acc[2][1] = fmaf(a2, b.y, acc[2][1]);
                acc[2][2] = fmaf(a2, b.z, acc[2][2]); acc[2][3] = fmaf(a2, b.w, acc[2][3]);
                acc[3][0] = fmaf(a3, b.x, acc[3][0]); acc[3][1] = fmaf(a3, b.y, acc[3][1]);
                acc[3][2] = fmaf(a3, b.z, acc[3][2]); acc[3][3] = fmaf(a3, b.w, acc[3][3]);
            }
        }

        const float4 b2v = *(const float4*)(b2 + (size_t)e * D_MODEL + n0 + tx * 4);
        #pragma unroll
        for (int i = 0; i < 4; ++i) {
            const int m = ty * 4 + i;
            if (m < rows) {
                const float gt = sg[m];
                const int   tk = stok[m];
                float* dst = out + (size_t)tk * D_MODEL + n0 + tx * 4;
                unsafeAtomicAdd(dst + 0, gt * (acc[i][0] + b2v.x));
                unsafeAtomicAdd(dst + 1, gt * (acc[i][1] + b2v.y));
                unsafeAtomicAdd(dst + 2, gt * (acc[i][2] + b2v.z));
                unsafeAtomicAdd(dst + 3, gt * (acc[i][3] + b2v.w));
            }
        }
        __syncthreads();
    }
}

// ---------------------------------------------------------------------------
extern "C" void kernel_launch(void* const* d_in, const int* in_sizes, int n_in,
                              void* d_out, int out_size, void* d_ws, size_t ws_size,
                              hipStream_t stream)
{
    const float* x     = (const float*)d_in[0];
    const float* noise = (const float*)d_in[1];
    const float* Wr    = (const float*)d_in[2];
    const float* br    = (const float*)d_in[3];
    const float* Wn    = (const float*)d_in[4];
    const float* bn    = (const float*)d_in[5];
    const float* W1    = (const float*)d_in[6];
    const float* b1    = (const float*)d_in[7];
    const float* W2    = (const float*)d_in[8];
    const float* b2    = (const float*)d_in[9];
    float* out = (float*)d_out;

    char* ws = (char*)d_ws;
    int*   counts    = (int*)(ws + WS_COUNTS);
    int*   cursor    = (int*)(ws + WS_CURSOR);
    int*   offsets   = (int*)(ws + WS_OFFSETS);
    int*   tok_e     = (int*)(ws + WS_TOKE);
    float* tok_g     = (float*)(ws + WS_TOKG);
    int*   list_tok  = (int*)(ws + WS_LTOK);
    float* list_gate = (float*)(ws + WS_LGATE);
    float* H         = (float*)(ws + WS_H);

    hipMemsetAsync(ws, 0, 128, stream);                                  // counts+cursor
    hipMemsetAsync(d_out, 0, (size_t)out_size * sizeof(float), stream);  // out accumulator

    k_router<<<T_TOK, 256, 0, stream>>>(x, noise, Wr, br, Wn, bn, counts, tok_e, tok_g);
    k_prefix<<<1, 64, 0, stream>>>(counts, offsets);
    k_scatter<<<NPAIR / 256, 256, 0, stream>>>(tok_e, tok_g, offsets, cursor,
                                               list_tok, list_gate);
    k_ffn1<<<dim3(HID / 64, 32, N_EXP), 256, 0, stream>>>(x, W1, b1, counts, offsets,
                                                          list_tok, H);
    k_ffn2<<<dim3(D_MODEL / 64, 32, N_EXP), 256, 0, stream>>>(H, W2, b2, counts, offsets,
                                                              list_tok, list_gate, out);
}

// Round 2
// 460.622 us; speedup vs baseline: 4.4643x; 4.4643x over previous
//
#include <hip/hip_runtime.h>
#include <hip/hip_bf16.h>
#include <cstdint>
#include <cstddef>

#define D_MODEL 1024
#define N_EXP   8
#define HID     4096
#define T_TOK   4096          // B*S
#define NPAIR   (T_TOK * 2)   // top-2

// ---------------- workspace layout (bytes) ----------------
#define WS_COUNTS   0
#define WS_CURSOR   32
#define WS_OFFSETS  64
#define WS_TOKE     128                       // tok_e[T][2] int
#define WS_TOKG     32896                     // tok_g[T][2] float
#define WS_LTOK     65664                     // list_tok[NPAIR] int
#define WS_LGATE    98432                     // list_gate[NPAIR] float
#define WS_XB       131328                    // xb[T][1024] bf16        (8 MB)
#define WS_WB       (WS_XB + 8388608)         // Wt shared buf bf16      (64 MB)
#define WS_H        (WS_WB + 67108864)        // H[NPAIR][4096] bf16     (64 MB)
// total ~142.7 MB

typedef __attribute__((ext_vector_type(8))) short bf16x8;
typedef __attribute__((ext_vector_type(4))) float f32x4;

__device__ __forceinline__ unsigned short f2bf(float f) {
    unsigned u = __float_as_uint(f);
    u += 0x7FFFu + ((u >> 16) & 1u);          // RNE
    return (unsigned short)(u >> 16);
}

__device__ __forceinline__ void glds16(const void* g, void* l) {
    __builtin_amdgcn_global_load_lds(
        (const __attribute__((address_space(1))) void*)g,
        (__attribute__((address_space(3))) void*)l, 16, 0, 0);
}

// ---------------------------------------------------------------------------
// Router (unchanged from validated baseline)
// ---------------------------------------------------------------------------
__global__ __launch_bounds__(256) void k_router(
    const float* __restrict__ x, const float* __restrict__ noise,
    const float* __restrict__ Wr, const float* __restrict__ br,
    const float* __restrict__ Wn, const float* __restrict__ bn,
    int* __restrict__ counts, int* __restrict__ tok_e, float* __restrict__ tok_g)
{
    const int t   = blockIdx.x;
    const int tid = threadIdx.x;
    const int e   = tid & 7;
    const int g   = tid >> 3;
    const float* xr = x + (size_t)t * D_MODEL;

    float ar = 0.f, an = 0.f;
    const int ibase = g * 32;
    #pragma unroll 8
    for (int j = 0; j < 32; ++j) {
        const int i = ibase + j;
        const float xv = xr[i];
        ar = fmaf(xv, Wr[i * 8 + e], ar);
        an = fmaf(xv, Wn[i * 8 + e], an);
    }

    __shared__ float sR[256], sN[256];
    sR[tid] = ar; sN[tid] = an;
    __syncthreads();
    for (int off = 128; off >= 8; off >>= 1) {
        if (tid < off) { sR[tid] += sR[tid + off]; sN[tid] += sN[tid + off]; }
        __syncthreads();
    }

    __shared__ float lg[8];
    if (tid < 8) {
        const float z  = sN[tid] + bn[tid];
        const float sp = fmaxf(z, 0.f) + log1pf(expf(-fabsf(z)));
        lg[tid] = sR[tid] + br[tid] + sp * noise[t * 8 + tid];
    }
    __syncthreads();

    if (tid == 0) {
        float v0 = -INFINITY, v1 = -INFINITY;
        int   i0 = 0,         i1 = 0;
        #pragma unroll
        for (int ee = 0; ee < 8; ++ee) {
            const float v = lg[ee];
            if (v > v0)      { v1 = v0; i1 = i0; v0 = v; i0 = ee; }
            else if (v > v1) { v1 = v;  i1 = ee; }
        }
        const float ew  = expf(v1 - v0);
        const float inv = 1.f / (1.f + ew);
        tok_e[t * 2 + 0] = i0;
        tok_e[t * 2 + 1] = i1;
        tok_g[t * 2 + 0] = inv;
        tok_g[t * 2 + 1] = ew * inv;
        atomicAdd(&counts[i0], 1);
        atomicAdd(&counts[i1], 1);
    }
}

__global__ void k_prefix(const int* __restrict__ counts, int* __restrict__ offsets)
{
    if (threadIdx.x == 0 && blockIdx.x == 0) {
        int acc = 0;
        #pragma unroll
        for (int e = 0; e < N_EXP; ++e) { offsets[e] = acc; acc += counts[e]; }
    }
}

__global__ __launch_bounds__(256) void k_scatter(
    const int* __restrict__ tok_e, const float* __restrict__ tok_g,
    const int* __restrict__ offsets, int* __restrict__ cursor,
    int* __restrict__ list_tok, float* __restrict__ list_gate)
{
    const int gid = blockIdx.x * 256 + threadIdx.x;
    if (gid >= NPAIR) return;
    const int e = tok_e[gid];
    const int p = atomicAdd(&cursor[e], 1);
    const int slot = offsets[e] + p;
    list_tok[slot]  = gid >> 1;
    list_gate[slot] = tok_g[gid];
}

// ---------------------------------------------------------------------------
// x f32 -> bf16 (flat)
// ---------------------------------------------------------------------------
__global__ __launch_bounds__(256) void k_cvt_x(
    const float* __restrict__ in, unsigned short* __restrict__ outp)
{
    const int i = (blockIdx.x * 256 + threadIdx.x) * 4;
    const float4 v = *(const float4*)(in + i);
    ushort4 o;
    o.x = f2bf(v.x); o.y = f2bf(v.y); o.z = f2bf(v.z); o.w = f2bf(v.w);
    *(ushort4*)(outp + i) = o;
}

// ---------------------------------------------------------------------------
// Per-expert transpose + convert: in f32 [E][R][C] -> out bf16 [E][C][R]
// 32x32 tiles via LDS. grid = (C/32, R/32, E), block 256.
// ---------------------------------------------------------------------------
__global__ __launch_bounds__(256) void k_cvtT(
    const float* __restrict__ in, unsigned short* __restrict__ outp, int R, int C)
{
    const size_t esz = (size_t)R * C;
    const float* ine = in + (size_t)blockIdx.z * esz;
    unsigned short* oute = outp + (size_t)blockIdx.z * esz;
    const int c0 = blockIdx.x * 32, r0 = blockIdx.y * 32;

    __shared__ float s[32][36];
    const int tid = threadIdx.x;
    const int lr = tid >> 3, lc = (tid & 7) * 4;
    const float4 v = *(const float4*)(ine + (size_t)(r0 + lr) * C + c0 + lc);
    s[lr][lc + 0] = v.x; s[lr][lc + 1] = v.y; s[lr][lc + 2] = v.z; s[lr][lc + 3] = v.w;
    __syncthreads();
    const int oc = tid >> 3, orp = (tid & 7) * 4;
    ushort4 o;
    o.x = f2bf(s[orp + 0][oc]); o.y = f2bf(s[orp + 1][oc]);
    o.z = f2bf(s[orp + 2][oc]); o.w = f2bf(s[orp + 3][oc]);
    *(ushort4*)(oute + (size_t)(c0 + oc) * R + r0 + orp) = o;
}

// ---------------------------------------------------------------------------
// Grouped MFMA GEMM1: H[slot,:] = relu( xb[tok[slot],:] @ W1t[e]^T + b1[e] )
// Tile 128x128, BK=32. 4 waves (2x2), each wave 64x64 = 4x4 frags of 16x16x32.
// A gathered by token via per-lane global_load_lds source addresses.
// grid = (HID/128, NPAIR/128, E), early exit on m0 >= cnt.
// ---------------------------------------------------------------------------
__global__ __launch_bounds__(256) void k_ffn1(
    const unsigned short* __restrict__ xb,     // [T][1024]
    const unsigned short* __restrict__ W1t,    // [E][4096][1024]  (n-major, k contig)
    const float* __restrict__ b1,              // [E][4096]
    const int* __restrict__ counts, const int* __restrict__ offsets,
    const int* __restrict__ list_tok,
    unsigned short* __restrict__ H)            // [NPAIR][4096]
{
    const int e   = blockIdx.z;
    const int cnt = counts[e];
    const int m0  = blockIdx.y * 128;
    if (m0 >= cnt) return;
    const int base = offsets[e];
    const int n0   = blockIdx.x * 128;
    const unsigned short* __restrict__ Be = W1t + (size_t)e * (HID * D_MODEL);

    __shared__ __align__(16) unsigned short As[128 * 32];
    __shared__ __align__(16) unsigned short Bs[128 * 32];
    __shared__ int stok[128];

    const int tid = threadIdx.x;
    if (tid < 128) stok[tid] = list_tok[base + min(m0 + tid, cnt - 1)];
    __syncthreads();

    const int arow  = tid >> 2;             // 0..63
    const int kpart = (tid & 3) * 8;        // bf16 offset in row
    const size_t srcA0 = (size_t)stok[arow]      * D_MODEL + kpart;
    const size_t srcA1 = (size_t)stok[arow + 64] * D_MODEL + kpart;
    const size_t srcB0 = (size_t)(n0 + arow)      * D_MODEL + kpart;
    const size_t srcB1 = (size_t)(n0 + arow + 64) * D_MODEL + kpart;

    const int lane = tid & 63, lr = lane & 15, hk = lane >> 4;
    const int w = tid >> 6, wm = w >> 1, wn = w & 1;
    const int aoff = (wm * 64 + lr) * 32 + hk * 8;   // ushort index
    const int boff = (wn * 64 + lr) * 32 + hk * 8;

    f32x4 acc[4][4] = {};

    for (int kt = 0; kt < D_MODEL; kt += 32) {
        __syncthreads();
        glds16(xb + srcA0 + kt, (char*)As + tid * 16);
        glds16(xb + srcA1 + kt, (char*)As + (tid + 256) * 16);
        glds16(Be + srcB0 + kt, (char*)Bs + tid * 16);
        glds16(Be + srcB1 + kt, (char*)Bs + (tid + 256) * 16);
        __syncthreads();   // compiler drains vmcnt before barrier

        bf16x8 a[4], b[4];
        #pragma unroll
        for (int i = 0; i < 4; ++i) a[i] = *(const bf16x8*)(As + aoff + i * 16 * 32);
        #pragma unroll
        for (int j = 0; j < 4; ++j) b[j] = *(const bf16x8*)(Bs + boff + j * 16 * 32);
        #pragma unroll
        for (int i = 0; i < 4; ++i)
            #pragma unroll
            for (int j = 0; j < 4; ++j)
                acc[i][j] = __builtin_amdgcn_mfma_f32_16x16x32_bf16(a[i], b[j], acc[i][j], 0, 0, 0);
    }

    float bias[4];
    #pragma unroll
    for (int j = 0; j < 4; ++j) bias[j] = b1[(size_t)e * HID + n0 + wn * 64 + j * 16 + lr];

    #pragma unroll
    for (int i = 0; i < 4; ++i) {
        #pragma unroll
        for (int g = 0; g < 4; ++g) {
            const int m = m0 + wm * 64 + i * 16 + hk * 4 + g;   // C/D: row=(l>>4)*4+g, col=l&15
            if (m < cnt) {
                unsigned short* dst = H + (size_t)(base + m) * HID + n0 + wn * 64 + lr;
                #pragma unroll
                for (int j = 0; j < 4; ++j)
                    dst[j * 16] = f2bf(fmaxf(acc[i][j][g] + bias[j], 0.f));
            }
        }
    }
}

// ---------------------------------------------------------------------------
// Grouped MFMA GEMM2: out[tok,:] += gate * ( H[slot,:] @ W2t[e]^T + b2[e] )
// Same structure, K=4096, N=1024. grid = (D_MODEL/128, NPAIR/128, E).
// ---------------------------------------------------------------------------
__global__ __launch_bounds__(256) void k_ffn2(
    const unsigned short* __restrict__ Hb,     // [NPAIR][4096]
    const unsigned short* __restrict__ W2t,    // [E][1024][4096]  (n-major, k contig)
    const float* __restrict__ b2,              // [E][1024]
    const int* __restrict__ counts, const int* __restrict__ offsets,
    const int* __restrict__ list_tok, const float* __restrict__ list_gate,
    float* __restrict__ out)
{
    const int e   = blockIdx.z;
    const int cnt = counts[e];
    const int m0  = blockIdx.y * 128;
    if (m0 >= cnt) return;
    const int base = offsets[e];
    const int n0   = blockIdx.x * 128;
    const unsigned short* __restrict__ Be = W2t + (size_t)e * (D_MODEL * HID);

    __shared__ __align__(16) unsigned short As[128 * 32];
    __shared__ __align__(16) unsigned short Bs[128 * 32];

    const int tid  = threadIdx.x;
    const int arow = tid >> 2;
    const int kpart = (tid & 3) * 8;
    const size_t srcA0 = (size_t)(base + min(m0 + arow,      cnt - 1)) * HID + kpart;
    const size_t srcA1 = (size_t)(base + min(m0 + arow + 64, cnt - 1)) * HID + kpart;
    const size_t srcB0 = (size_t)(n0 + arow)      * HID + kpart;
    const size_t srcB1 = (size_t)(n0 + arow + 64) * HID + kpart;

    const int lane = tid & 63, lr = lane & 15, hk = lane >> 4;
    const int w = tid >> 6, wm = w >> 1, wn = w & 1;
    const int aoff = (wm * 64 + lr) * 32 + hk * 8;
    const int boff = (wn * 64 + lr) * 32 + hk * 8;

    f32x4 acc[4][4] = {};

    for (int kt = 0; kt < HID; kt += 32) {
        __syncthreads();
        glds16(Hb + srcA0 + kt, (char*)As + tid * 16);
        glds16(Hb + srcA1 + kt, (char*)As + (tid + 256) * 16);
        glds16(Be + srcB0 + kt, (char*)Bs + tid * 16);
        glds16(Be + srcB1 + kt, (char*)Bs + (tid + 256) * 16);
        __syncthreads();

        bf16x8 a[4], b[4];
        #pragma unroll
        for (int i = 0; i < 4; ++i) a[i] = *(const bf16x8*)(As + aoff + i * 16 * 32);
        #pragma unroll
        for (int j = 0; j < 4; ++j) b[j] = *(const bf16x8*)(Bs + boff + j * 16 * 32);
        #pragma unroll
        for (int i = 0; i < 4; ++i)
            #pragma unroll
            for (int j = 0; j < 4; ++j)
                acc[i][j] = __builtin_amdgcn_mfma_f32_16x16x32_bf16(a[i], b[j], acc[i][j], 0, 0, 0);
    }

    float bias[4];
    #pragma unroll
    for (int j = 0; j < 4; ++j) bias[j] = b2[(size_t)e * D_MODEL + n0 + wn * 64 + j * 16 + lr];

    #pragma unroll
    for (int i = 0; i < 4; ++i) {
        #pragma unroll
        for (int g = 0; g < 4; ++g) {
            const int m = m0 + wm * 64 + i * 16 + hk * 4 + g;
            if (m < cnt) {
                const int sl = base + m;
                const int tk = list_tok[sl];
                const float gt = list_gate[sl];
                float* dst = out + (size_t)tk * D_MODEL + n0 + wn * 64 + lr;
                #pragma unroll
                for (int j = 0; j < 4; ++j)
                    unsafeAtomicAdd(dst + j * 16, gt * (acc[i][j][g] + bias[j]));
            }
        }
    }
}

// ---------------------------------------------------------------------------
extern "C" void kernel_launch(void* const* d_in, const int* in_sizes, int n_in,
                              void* d_out, int out_size, void* d_ws, size_t ws_size,
                              hipStream_t stream)
{
    const float* x     = (const float*)d_in[0];
    const float* noise = (const float*)d_in[1];
    const float* Wr    = (const float*)d_in[2];
    const float* br    = (const float*)d_in[3];
    const float* Wn    = (const float*)d_in[4];
    const float* bn    = (const float*)d_in[5];
    const float* W1    = (const float*)d_in[6];
    const float* b1    = (const float*)d_in[7];
    const float* W2    = (const float*)d_in[8];
    const float* b2    = (const float*)d_in[9];
    float* out = (float*)d_out;

    char* ws = (char*)d_ws;
    int*   counts    = (int*)(ws + WS_COUNTS);
    int*   cursor    = (int*)(ws + WS_CURSOR);
    int*   offsets   = (int*)(ws + WS_OFFSETS);
    int*   tok_e     = (int*)(ws + WS_TOKE);
    float* tok_g     = (float*)(ws + WS_TOKG);
    int*   list_tok  = (int*)(ws + WS_LTOK);
    float* list_gate = (float*)(ws + WS_LGATE);
    unsigned short* xb = (unsigned short*)(ws + WS_XB);
    unsigned short* Wb = (unsigned short*)(ws + WS_WB);
    unsigned short* Hb = (unsigned short*)(ws + WS_H);

    hipMemsetAsync(ws, 0, 128, stream);
    hipMemsetAsync(d_out, 0, (size_t)out_size * sizeof(float), stream);

    // conversions + routing
    k_cvt_x<<<T_TOK * D_MODEL / 1024, 256, 0, stream>>>(x, xb);
    k_cvtT<<<dim3(HID / 32, D_MODEL / 32, N_EXP), 256, 0, stream>>>(W1, Wb, D_MODEL, HID);
    k_router<<<T_TOK, 256, 0, stream>>>(x, noise, Wr, br, Wn, bn, counts, tok_e, tok_g);
    k_prefix<<<1, 64, 0, stream>>>(counts, offsets);
    k_scatter<<<NPAIR / 256, 256, 0, stream>>>(tok_e, tok_g, offsets, cursor,
                                               list_tok, list_gate);

    // FFN1 (uses Wb = W1t)
    k_ffn1<<<dim3(HID / 128, NPAIR / 128, N_EXP), 256, 0, stream>>>(
        xb, Wb, b1, counts, offsets, list_tok, Hb);

    // convert W2 into the same Wb buffer, then FFN2
    k_cvtT<<<dim3(D_MODEL / 32, HID / 32, N_EXP), 256, 0, stream>>>(W2, Wb, HID, D_MODEL);
    k_ffn2<<<dim3(D_MODEL / 128, NPAIR / 128, N_EXP), 256, 0, stream>>>(
        Hb, Wb, b2, counts, offsets, list_tok, list_gate, out);
}